// Round 22
// baseline (533.988 us; speedup 1.0000x reference)
//
#include <hip/hip_runtime.h>
#include <hip/hip_bf16.h>
#include <math.h>

// ---------------- constants ----------------
#define B 32
#define SEQ 512
#define NTOK 680           // 512+128+32+8
#define DM 256
#define FF 512
#define NROWS (B*NTOK)     // 21760

using bf16x8 = __attribute__((ext_vector_type(8))) short;
using f32x4  = __attribute__((ext_vector_type(4))) float;
using u32x4  = __attribute__((ext_vector_type(4))) unsigned int;
typedef __hip_bfloat16 bf16;

__device__ __forceinline__ unsigned short f2bf(float f) {
    union { float f; unsigned u; } x; x.f = f;
    unsigned r = (x.u + 0x7fffu + ((x.u >> 16) & 1u)) >> 16;
    return (unsigned short)r;
}
__device__ __forceinline__ float bfu2f(unsigned short u) {
    union { unsigned u; float f; } x; x.u = ((unsigned)u) << 16;
    return x.f;
}
__device__ __forceinline__ void dotu(unsigned a, unsigned b, float& s) {
    union { unsigned u; float f; } al, ah, bl, bh;
    al.u = a << 16; ah.u = a & 0xffff0000u;
    bl.u = b << 16; bh.u = b & 0xffff0000u;
    s = fmaf(al.f, bl.f, s);
    s = fmaf(ah.f, bh.f, s);
}

// ---------------- embedding (writes fp32 X rows + contiguous bf16 Xe) ----------------
__global__ __launch_bounds__(256) void emb_kernel(
    const float* __restrict__ x_enc, const float* __restrict__ x_mark,
    const float* __restrict__ W_val, const float* __restrict__ W_time,
    const float* __restrict__ b_time, float* __restrict__ X, bf16* __restrict__ Xe)
{
    int bs = blockIdx.x;
    int b = bs >> 9, s = bs & 511;
    int d = threadIdx.x;
    int sm1 = (s + 511) & 511, sp1 = (s + 1) & 511;
    float x0 = x_enc[b*512 + sm1];
    float x1 = x_enc[b*512 + s];
    float x2 = x_enc[b*512 + sp1];
    float val = x0 * W_val[d*3+0] + x1 * W_val[d*3+1] + x2 * W_val[d*3+2];
    const float* mk = &x_mark[(size_t)bs*4];
    float tm = mk[0]*W_time[d] + mk[1]*W_time[256+d] + mk[2]*W_time[512+d] + mk[3]*W_time[768+d];
    int i2 = d & ~1;
    float div = expf((float)i2 * (-9.210340371976184f / 256.0f));
    float ang = (float)s * div;
    float pe = (d & 1) ? cosf(ang) : sinf(ang);
    float out = val + tm + b_time[d] + pe;
    X[((size_t)(b*NTOK + s))*DM + d] = out;
    ((unsigned short*)Xe)[(size_t)bs*DM + d] = f2bf(out);
}

// ---------------- CSCM strided conv + BN affine + ELU ----------------
__global__ __launch_bounds__(64) void conv_kernel(
    const float* __restrict__ in, int inRPB, int inOff,
    float* __restrict__ Pool, int outOff, int Lout,
    const float* __restrict__ W_conv, const float* __restrict__ b_conv,
    const float* __restrict__ bn_g, const float* __restrict__ bn_b, int sc)
{
    __shared__ float lds[256];
    int blk = blockIdx.x;
    int b = blk / Lout, p = blk % Lout;
    int t = threadIdx.x;
    for (int u = t; u < 256; u += 64)
        lds[u] = in[((size_t)(b*inRPB + inOff + p*4 + (u >> 6)))*64 + (u & 63)];
    __syncthreads();
    float acc = b_conv[sc*64 + t];
    const float* w = &W_conv[(size_t)(sc*64 + t)*256];
    #pragma unroll 4
    for (int ci = 0; ci < 64; ++ci) {
        #pragma unroll
        for (int tap = 0; tap < 4; ++tap)
            acc = fmaf(lds[tap*64 + ci], w[ci*4 + tap], acc);
    }
    float v = acc * bn_g[sc*64 + t] + bn_b[sc*64 + t];
    v = v > 0.f ? v : expm1f(v);
    Pool[((size_t)(b*168 + outOff + p))*64 + t] = v;
}

// ---------------- CSCM up-projection ----------------
__global__ __launch_bounds__(256) void up_kernel(
    const float* __restrict__ Pool, const float* __restrict__ W_up,
    const float* __restrict__ b_up, float* __restrict__ X)
{
    __shared__ float row[64];
    int blk = blockIdx.x;
    int b = blk / 168, p = blk % 168;
    int d = threadIdx.x;
    if (d < 64) row[d] = Pool[(size_t)blk*64 + d];
    __syncthreads();
    float acc = b_up[d];
    #pragma unroll 8
    for (int k = 0; k < 64; ++k) acc = fmaf(row[k], W_up[k*256 + d], acc);
    X[((size_t)(b*NTOK + 512 + p))*DM + d] = acc;
}

// ---------------- LayerNorm (prologue): fp32 in, bf16 out ----------------
__global__ __launch_bounds__(256) void ln_kernel(
    const float* __restrict__ Xf, bf16* __restrict__ Xio,
    const float* __restrict__ g, const float* __restrict__ bta)
{
    int r = blockIdx.x*4 + (threadIdx.x >> 6);
    int lane = threadIdx.x & 63;
    float4 v = ((const float4*)(Xf + (size_t)r*DM))[lane];
    float s = v.x + v.y + v.z + v.w;
    #pragma unroll
    for (int o = 32; o; o >>= 1) s += __shfl_xor(s, o);
    float mean = s * (1.0f/256.0f);
    float dx = v.x-mean, dy = v.y-mean, dz = v.z-mean, dw = v.w-mean;
    float q = dx*dx + dy*dy + dz*dz + dw*dw;
    #pragma unroll
    for (int o = 32; o; o >>= 1) q += __shfl_xor(q, o);
    float inv = rsqrtf(q*(1.0f/256.0f) + 1e-5f);
    float4 gg = ((const float4*)g)[lane];
    float4 bb = ((const float4*)bta)[lane];
    float ox = dx*inv*gg.x + bb.x;
    float oy = dy*inv*gg.y + bb.y;
    float oz = dz*inv*gg.z + bb.z;
    float ow = dw*inv*gg.w + bb.w;
    unsigned u0 = (unsigned)f2bf(ox) | ((unsigned)f2bf(oy) << 16);
    unsigned u1 = (unsigned)f2bf(oz) | ((unsigned)f2bf(ow) << 16);
    ((uint2*)(Xio + (size_t)r*DM))[lane] = make_uint2(u0, u1);
}

// ---------------- neighbor lists: closed form ----------------
__global__ void nbr_kernel(int* __restrict__ nbr, int* __restrict__ ncnt)
{
    int i = blockIdx.x * 64 + threadIdx.x;
    if (i >= NTOK) return;
    const int starts[5] = {0, 512, 640, 672, 680};
    int si = (i < 512) ? 0 : (i < 640) ? 1 : (i < 672) ? 2 : 3;
    int st = starts[si], en = starts[si+1];
    int idx = i - st;
    int cnt = 0;
    if (si >= 1) {
        int cs = starts[si-1] + idx*4;
        #pragma unroll
        for (int c = 0; c < 4; ++c) nbr[i*16 + cnt++] = cs + c;
    }
    int lo = (i-2 > st) ? i-2 : st;
    int hi = (i+2 < en-1) ? i+2 : en-1;
    for (int j = lo; j <= hi; ++j) nbr[i*16 + cnt++] = j;
    if (si <= 2) nbr[i*16 + cnt++] = starts[si+1] + (idx >> 2);
    ncnt[i] = cnt;
}

// ---------------- weight transpose + bf16 convert: 32x32 LDS tiles ----------------
struct WDesc { const float* src; bf16* dst; int K; int N; };
struct WTable { WDesc d[13]; };
__global__ __launch_bounds__(256) void wconv_kernel(WTable tbl)
{
    __shared__ float lds[32][33];
    WDesc ds = tbl.d[blockIdx.y];
    int ntn = ds.N >> 5;
    int ntiles = (ds.K >> 5) * ntn;
    int tile = blockIdx.x;
    if (tile >= ntiles) return;
    int k0 = (tile / ntn) * 32, n0 = (tile % ntn) * 32;
    int t = threadIdx.x;
    int r = t >> 3, c4 = (t & 7) * 4;
    float4 v = *(const float4*)(ds.src + (size_t)(k0 + r)*ds.N + n0 + c4);
    lds[r][c4+0] = v.x; lds[r][c4+1] = v.y; lds[r][c4+2] = v.z; lds[r][c4+3] = v.w;
    __syncthreads();
    unsigned u0 = (unsigned)f2bf(lds[c4+0][r]) | ((unsigned)f2bf(lds[c4+1][r]) << 16);
    unsigned u1 = (unsigned)f2bf(lds[c4+2][r]) | ((unsigned)f2bf(lds[c4+3][r]) << 16);
    *(uint2*)((unsigned short*)ds.dst + (size_t)(n0 + r)*ds.K + k0 + c4) = make_uint2(u0, u1);
}

// ---------------- Wp transpose (f32): WpT[o][k] = Wp[k][o] ----------------
__global__ __launch_bounds__(256) void wpt_kernel(
    const float* __restrict__ Wp, float* __restrict__ WpT)
{
    int e = blockIdx.x*256 + threadIdx.x;
    int o = e % 96, k = e / 96;
    WpT[(size_t)o*1024 + k] = Wp[(size_t)k*96 + o];
}

// ---------------- FUSED QKV projection (32 rows, 8 waves) ----------------
__global__ __launch_bounds__(512, 2) void qkv_kernel(
    const bf16* __restrict__ Xh,
    const bf16* __restrict__ WqT, const bf16* __restrict__ WkT, const bf16* __restrict__ WvT,
    const float* __restrict__ bq, const float* __restrict__ bk, const float* __restrict__ bv,
    bf16* __restrict__ Qh, bf16* __restrict__ Kh, bf16* __restrict__ Vh)
{
    __shared__ __align__(16) char smem[16384 + 16896];   // A 16KB | ctb [32][264] bf16
    uint4* AsU = (uint4*)smem;
    const bf16x8* Asv = (const bf16x8*)smem;
    unsigned short* ctb = (unsigned short*)(smem + 16384);

    int t = threadIdx.x;
    int lane = t & 63, w = t >> 6;
    int nwg = gridDim.x;                                 // 680, %8==0
    int wg = (blockIdx.x & 7) * (nwg >> 3) + (blockIdx.x >> 3);
    int row0 = wg * 32;
    const unsigned short* Xu = (const unsigned short*)Xh;

    #pragma unroll
    for (int i = 0; i < 2; ++i) {
        int gg = t + i*512, r = gg >> 5, c = gg & 31;
        AsU[r*32 + (c ^ (r & 7))] = *(const uint4*)(Xu + (size_t)(row0 + r)*DM + c*8);
    }
    __syncthreads();

    #pragma unroll
    for (int z = 0; z < 3; ++z) {
        const unsigned short* Wu = (const unsigned short*)((z == 0) ? WqT : (z == 1) ? WkT : WvT);
        const float* bias = (z == 0) ? bq : (z == 1) ? bk : bv;
        bf16* Op = (z == 0) ? Qh : (z == 1) ? Kh : Vh;

        f32x4 acc[2][2];
        #pragma unroll
        for (int m = 0; m < 2; ++m)
            #pragma unroll
            for (int nn = 0; nn < 2; ++nn)
                #pragma unroll
                for (int q = 0; q < 4; ++q) acc[m][nn][q] = 0.f;
        float bv_[2];
        #pragma unroll
        for (int nn = 0; nn < 2; ++nn) bv_[nn] = bias[w*32 + nn*16 + (lane & 15)];

        #pragma unroll
        for (int kh = 0; kh < 2; ++kh) {
            bf16x8 pw[8];
            #pragma unroll
            for (int i = 0; i < 8; ++i) {
                int kt = kh*128 + (i >> 1)*32, nn = i & 1;
                int nrow = w*32 + nn*16 + (lane & 15);
                pw[i] = *(const bf16x8*)(Wu + (size_t)nrow*256 + kt + (lane >> 4)*8);
            }
            #pragma unroll
            for (int ki = 0; ki < 4; ++ki) {
                int kt = kh*128 + ki*32;
                int cg = (kt >> 3) + (lane >> 4);
                bf16x8 af[2];
                #pragma unroll
                for (int m = 0; m < 2; ++m) {
                    int ar = m*16 + (lane & 15);
                    af[m] = Asv[ar*32 + (cg ^ (ar & 7))];
                }
                #pragma unroll
                for (int nn = 0; nn < 2; ++nn)
                    #pragma unroll
                    for (int m = 0; m < 2; ++m)
                        acc[m][nn] = __builtin_amdgcn_mfma_f32_16x16x32_bf16(af[m], pw[ki*2+nn], acc[m][nn], 0, 0, 0);
            }
        }

        __syncthreads();
        #pragma unroll
        for (int m = 0; m < 2; ++m)
            #pragma unroll
            for (int nn = 0; nn < 2; ++nn) {
                int col = w*32 + nn*16 + (lane & 15);
                #pragma unroll
                for (int q = 0; q < 4; ++q) {
                    int row = m*16 + (lane >> 4)*4 + q;
                    ctb[row*264 + col] = f2bf(acc[m][nn][q] + bv_[nn]);
                }
            }
        __syncthreads();
        #pragma unroll
        for (int i = 0; i < 2; ++i) {
            int idx = t + i*512;
            int row = idx >> 5, c16 = idx & 31;
            u32x4 uv = *(const u32x4*)(ctb + row*264 + c16*8);
            *(u32x4*)((unsigned short*)Op + (size_t)(row0 + row)*DM + c16*8) = uv;
        }
    }
}

// ---------------- FUSED attn + Wo + LN1 + FFN + LN2 (32 rows, 8 waves) ----------------
// Phase 0: sparse attention for the block's own 32 rows (shuffle-only softmax),
// writing results DIRECTLY into the swizzled LDS A-tile (Obh tensor eliminated).
// Then: Wo proj -> LN1 (xmid back into A-tile) -> FF1 (both halves in regs) ->
// hidden tile -> FF2 -> LN2 -> Xh.
#define CSTR 260
#define HSTR2 520
__global__ __launch_bounds__(512, 2) void layerfull_kernel(
    const bf16* __restrict__ Qh, const bf16* __restrict__ Kh, const bf16* __restrict__ Vh,
    bf16* __restrict__ Xh,
    const bf16* __restrict__ WoT, const float* __restrict__ bo,
    const float* __restrict__ g1, const float* __restrict__ b1n,
    const bf16* __restrict__ W1t, const float* __restrict__ b1,
    const bf16* __restrict__ W2t, const float* __restrict__ b2,
    const float* __restrict__ g2, const float* __restrict__ b2n,
    const int* __restrict__ nbr, const int* __restrict__ ncnt)
{
    __shared__ __align__(16) char smem[16384 + 33280];   // A 16KB | union(ctile f32 [32][260], hT bf16 [32][520])
    uint4* AsU = (uint4*)smem;
    const bf16x8* Asv = (const bf16x8*)smem;
    unsigned short* Asu16 = (unsigned short*)smem;
    float* ctile = (float*)(smem + 16384);
    unsigned short* hT = (unsigned short*)(smem + 16384);

    int t = threadIdx.x;
    int lane = t & 63, w = t >> 6;
    int nwg = gridDim.x;                                 // 680
    int wg = (blockIdx.x & 7) * (nwg >> 3) + (blockIdx.x >> 3);
    int row0 = wg * 32;
    const unsigned short* Qu = (const unsigned short*)Qh;
    const unsigned short* Ku = (const unsigned short*)Kh;
    const unsigned short* Vu = (const unsigned short*)Vh;
    const unsigned short* Xu  = (const unsigned short*)Xh;
    const unsigned short* WoU = (const unsigned short*)WoT;
    const unsigned short* W1u = (const unsigned short*)W1t;
    const unsigned short* W2u = (const unsigned short*)W2t;

    // ---- phase 0: sparse attention for own 32 rows -> AsU (swizzled bf16)
    {
        int j = lane >> 2, g = lane & 3;
        #pragma unroll
        for (int rr = 0; rr < 4; ++rr) {
            int row = w*4 + rr;
            int grow = row0 + row;
            int n = grow % NTOK, b = grow / NTOK;
            int cnt = ncnt[n];
            int nj = (j < cnt) ? nbr[n*16 + j] : n;
            int jr = b*NTOK + nj;
            float p[4];
            #pragma unroll
            for (int h = 0; h < 4; ++h) {
                const uint4* qp = (const uint4*)(Qu + (size_t)grow*DM + h*64 + g*16);
                const uint4* kp = (const uint4*)(Ku + (size_t)jr*DM + h*64 + g*16);
                uint4 qa = qp[0], qb = qp[1];
                uint4 ka = kp[0], kb = kp[1];
                float s = 0.f;
                dotu(qa.x, ka.x, s); dotu(qa.y, ka.y, s); dotu(qa.z, ka.z, s); dotu(qa.w, ka.w, s);
                dotu(qb.x, kb.x, s); dotu(qb.y, kb.y, s); dotu(qb.z, kb.z, s); dotu(qb.w, kb.w, s);
                s += __shfl_xor(s, 1);
                s += __shfl_xor(s, 2);
                s *= 0.125f;
                if (j >= cnt) s = -1e30f;
                float m = s;
                #pragma unroll
                for (int o = 4; o < 64; o <<= 1) m = fmaxf(m, __shfl_xor(m, o));
                float wgt = (j < cnt) ? expf(s - m) : 0.f;
                float den = wgt;
                #pragma unroll
                for (int o = 4; o < 64; o <<= 1) den += __shfl_xor(den, o);
                p[h] = wgt / den;
            }
            // PV with lane = dim; shuffle-broadcast p and jr from lane jj*4
            #pragma unroll
            for (int h = 0; h < 4; ++h) {
                float acc = 0.f;
                for (int jj = 0; jj < cnt; ++jj) {
                    float wv = __shfl(p[h], jj*4);
                    int rr2 = __shfl(jr, jj*4);
                    acc = fmaf(wv, bfu2f(Vu[(size_t)rr2*DM + h*64 + lane]), acc);
                }
                int col = h*64 + lane;
                Asu16[row*256 + (((col >> 3) ^ (row & 7))*8) + (col & 7)] = f2bf(acc);
            }
        }
    }
    __syncthreads();                                     // (1) A-tile (attn out) complete

    // ---- Wo projection -> ctile
    {
        f32x4 acc[2][2];
        #pragma unroll
        for (int m = 0; m < 2; ++m)
            #pragma unroll
            for (int nn = 0; nn < 2; ++nn)
                #pragma unroll
                for (int q = 0; q < 4; ++q) acc[m][nn][q] = 0.f;
        float bvv[2];
        #pragma unroll
        for (int nn = 0; nn < 2; ++nn) bvv[nn] = bo[w*32 + nn*16 + (lane & 15)];

        #pragma unroll
        for (int kh = 0; kh < 2; ++kh) {
            bf16x8 pw[8];
            #pragma unroll
            for (int i = 0; i < 8; ++i) {
                int kt = kh*128 + (i >> 1)*32, nn = i & 1;
                int nrow = w*32 + nn*16 + (lane & 15);
                pw[i] = *(const bf16x8*)(WoU + (size_t)nrow*256 + kt + (lane >> 4)*8);
            }
            #pragma unroll
            for (int ki = 0; ki < 4; ++ki) {
                int kt = kh*128 + ki*32;
                int cg = (kt >> 3) + (lane >> 4);
                bf16x8 af[2];
                #pragma unroll
                for (int m = 0; m < 2; ++m) {
                    int ar = m*16 + (lane & 15);
                    af[m] = Asv[ar*32 + (cg ^ (ar & 7))];
                }
                #pragma unroll
                for (int nn = 0; nn < 2; ++nn)
                    #pragma unroll
                    for (int m = 0; m < 2; ++m)
                        acc[m][nn] = __builtin_amdgcn_mfma_f32_16x16x32_bf16(af[m], pw[ki*2+nn], acc[m][nn], 0, 0, 0);
            }
        }

        #pragma unroll
        for (int m = 0; m < 2; ++m)
            #pragma unroll
            for (int nn = 0; nn < 2; ++nn) {
                int col = w*32 + nn*16 + (lane & 15);
                #pragma unroll
                for (int q = 0; q < 4; ++q) {
                    int row = m*16 + (lane >> 4)*4 + q;
                    ctile[row*CSTR + col] = acc[m][nn][q] + bvv[nn];
                }
            }
    }
    __syncthreads();                                     // (2)

    // ---- LN1: xmid = LN(ctile + Xh); write xmid bf16 into AsU (swizzled)
    #pragma unroll
    for (int rr = 0; rr < 4; ++rr) {
        int row = w*4 + rr;
        float4 v = *(const float4*)(ctile + row*CSTR + lane*4);
        uint2 xu = *(const uint2*)(Xu + (size_t)(row0 + row)*DM + lane*4);
        v.x += bfu2f((unsigned short)(xu.x & 0xffffu));
        v.y += bfu2f((unsigned short)(xu.x >> 16));
        v.z += bfu2f((unsigned short)(xu.y & 0xffffu));
        v.w += bfu2f((unsigned short)(xu.y >> 16));
        float s = v.x + v.y + v.z + v.w;
        #pragma unroll
        for (int o = 32; o; o >>= 1) s += __shfl_xor(s, o);
        float mean = s * (1.0f/256.0f);
        float dx = v.x-mean, dy = v.y-mean, dz = v.z-mean, dw = v.w-mean;
        float q2 = dx*dx + dy*dy + dz*dz + dw*dw;
        #pragma unroll
        for (int o = 32; o; o >>= 1) q2 += __shfl_xor(q2, o);
        float inv = rsqrtf(q2*(1.0f/256.0f) + 1e-5f);
        float4 gg = ((const float4*)g1)[lane];
        float4 bb = ((const float4*)b1n)[lane];
        float ox = dx*inv*gg.x + bb.x;
        float oy = dy*inv*gg.y + bb.y;
        float oz = dz*inv*gg.z + bb.z;
        float ow = dw*inv*gg.w + bb.w;
        unsigned u0 = (unsigned)f2bf(ox) | ((unsigned)f2bf(oy) << 16);
        unsigned u1 = (unsigned)f2bf(oz) | ((unsigned)f2bf(ow) << 16);
        *(uint2*)(Asu16 + row*256 + (((lane>>1) ^ (row & 7))*8) + (lane & 1)*4) = make_uint2(u0, u1);
    }
    __syncthreads();                                     // (3)

    // ---- FF1: both halves in registers (64 hidden cols per wave)
    f32x4 acc1[2][2][2];   // [half][m][nn]
    #pragma unroll
    for (int hf = 0; hf < 2; ++hf)
        #pragma unroll
        for (int m = 0; m < 2; ++m)
            #pragma unroll
            for (int nn = 0; nn < 2; ++nn)
                #pragma unroll
                for (int q = 0; q < 4; ++q) acc1[hf][m][nn][q] = 0.f;

    #pragma unroll
    for (int hf = 0; hf < 2; ++hf) {
        #pragma unroll
        for (int kh = 0; kh < 2; ++kh) {
            bf16x8 pw[8];
            #pragma unroll
            for (int i = 0; i < 8; ++i) {
                int kt = kh*128 + (i >> 1)*32, nn = i & 1;
                int nrow = hf*256 + w*32 + nn*16 + (lane & 15);
                pw[i] = *(const bf16x8*)(W1u + (size_t)nrow*256 + kt + (lane >> 4)*8);
            }
            #pragma unroll
            for (int ki = 0; ki < 4; ++ki) {
                int kt = kh*128 + ki*32;
                int cg = (kt >> 3) + (lane >> 4);
                bf16x8 af[2];
                #pragma unroll
                for (int m = 0; m < 2; ++m) {
                    int ar = m*16 + (lane & 15);
                    af[m] = Asv[ar*32 + (cg ^ (ar & 7))];
                }
                #pragma unroll
                for (int nn = 0; nn < 2; ++nn)
                    #pragma unroll
                    for (int m = 0; m < 2; ++m)
                        acc1[hf][m][nn] = __builtin_amdgcn_mfma_f32_16x16x32_bf16(af[m], pw[ki*2+nn], acc1[hf][m][nn], 0, 0, 0);
            }
        }
    }
    #pragma unroll
    for (int hf = 0; hf < 2; ++hf) {
        float b1v[2];
        #pragma unroll
        for (int nn = 0; nn < 2; ++nn) b1v[nn] = b1[hf*256 + w*32 + nn*16 + (lane & 15)];
        #pragma unroll
        for (int m = 0; m < 2; ++m)
            #pragma unroll
            for (int nn = 0; nn < 2; ++nn) {
                int col = hf*256 + w*32 + nn*16 + (lane & 15);
                #pragma unroll
                for (int q = 0; q < 4; ++q) {
                    int row = m*16 + (lane >> 4)*4 + q;
                    hT[row*HSTR2 + col] = f2bf(fmaxf(acc1[hf][m][nn][q] + b1v[nn], 0.f));
                }
            }
    }
    __syncthreads();                                     // (4)

    // ---- FF2: single K=512 sweep
    f32x4 acc2[2][2];
    #pragma unroll
    for (int m = 0; m < 2; ++m)
        #pragma unroll
        for (int nn = 0; nn < 2; ++nn)
            #pragma unroll
            for (int q = 0; q < 4; ++q) acc2[m][nn][q] = 0.f;
    float b2v[2];
    #pragma unroll
    for (int nn = 0; nn < 2; ++nn) b2v[nn] = b2[w*32 + nn*16 + (lane & 15)];

    #pragma unroll
    for (int kh = 0; kh < 4; ++kh) {
        bf16x8 pw[8];
        #pragma unroll
        for (int i = 0; i < 8; ++i) {
            int kt = kh*128 + (i >> 1)*32, nn = i & 1;
            int nrow = w*32 + nn*16 + (lane & 15);
            pw[i] = *(const bf16x8*)(W2u + (size_t)nrow*512 + kt + (lane >> 4)*8);
        }
        #pragma unroll
        for (int ki = 0; ki < 4; ++ki) {
            int kt = kh*128 + ki*32;
            bf16x8 af[2];
            #pragma unroll
            for (int m = 0; m < 2; ++m) {
                int ar = m*16 + (lane & 15);
                af[m] = *(const bf16x8*)(hT + ar*HSTR2 + kt + (lane >> 4)*8);
            }
            #pragma unroll
            for (int nn = 0; nn < 2; ++nn)
                #pragma unroll
                for (int m = 0; m < 2; ++m)
                    acc2[m][nn] = __builtin_amdgcn_mfma_f32_16x16x32_bf16(af[m], pw[ki*2+nn], acc2[m][nn], 0, 0, 0);
        }
    }
    __syncthreads();                                     // (5)

    // ---- epilogue: ctile = acc2 + b2
    #pragma unroll
    for (int m = 0; m < 2; ++m)
        #pragma unroll
        for (int nn = 0; nn < 2; ++nn) {
            int col = w*32 + nn*16 + (lane & 15);
            #pragma unroll
            for (int q = 0; q < 4; ++q) {
                int row = m*16 + (lane >> 4)*4 + q;
                ctile[row*CSTR + col] = acc2[m][nn][q] + b2v[nn];
            }
        }
    __syncthreads();                                     // (6)
    // ---- LN2: Xh = LN(ctile + xmid from AsU)
    #pragma unroll
    for (int rr = 0; rr < 4; ++rr) {
        int row = w*4 + rr;
        float4 v = *(const float4*)(ctile + row*CSTR + lane*4);
        uint2 xu = *(const uint2*)(Asu16 + row*256 + (((lane>>1) ^ (row & 7))*8) + (lane & 1)*4);
        v.x += bfu2f((unsigned short)(xu.x & 0xffffu));
        v.y += bfu2f((unsigned short)(xu.x >> 16));
        v.z += bfu2f((unsigned short)(xu.y & 0xffffu));
        v.w += bfu2f((unsigned short)(xu.y >> 16));
        float s = v.x + v.y + v.z + v.w;
        #pragma unroll
        for (int o = 32; o; o >>= 1) s += __shfl_xor(s, o);
        float mean = s * (1.0f/256.0f);
        float dx = v.x-mean, dy = v.y-mean, dz = v.z-mean, dw = v.w-mean;
        float q2 = dx*dx + dy*dy + dz*dz + dw*dw;
        #pragma unroll
        for (int o = 32; o; o >>= 1) q2 += __shfl_xor(q2, o);
        float inv = rsqrtf(q2*(1.0f/256.0f) + 1e-5f);
        float4 gg = ((const float4*)g2)[lane];
        float4 bb = ((const float4*)b2n)[lane];
        float ox = dx*inv*gg.x + bb.x;
        float oy = dy*inv*gg.y + bb.y;
        float oz = dz*inv*gg.z + bb.z;
        float ow = dw*inv*gg.w + bb.w;
        unsigned u0 = (unsigned)f2bf(ox) | ((unsigned)f2bf(oy) << 16);
        unsigned u1 = (unsigned)f2bf(oz) | ((unsigned)f2bf(ow) << 16);
        *(uint2*)((unsigned short*)Xh + (size_t)(row0 + row)*DM + lane*4) = make_uint2(u0, u1);
    }
}

// ---------------- MFMA bf16 GEMM, 128x64 (down-projection, f32 out) ----------------
__global__ __launch_bounds__(256) void mfma_gemm_dn(
    const bf16* __restrict__ A, const bf16* __restrict__ Wt,
    const float* __restrict__ bias, float* __restrict__ Op)
{
    __shared__ __align__(16) char smem[34816];
    uint4* AsU = (uint4*)smem;
    uint4* BsU = (uint4*)(smem + 16384);
    const bf16x8* Asv = (const bf16x8*)smem;
    const bf16x8* Bsv = (const bf16x8*)(smem + 16384);
    const int KD = 256, Nc = 64;

    int t = threadIdx.x;
    int lane = t & 63, wid = t >> 6;
    int wm = wid >> 1, wn = wid & 1;
    int nwg = gridDim.x;
    int wg = (blockIdx.x & 7) * (nwg >> 3) + (blockIdx.x >> 3);
    int row0 = wg * 128;
    int n0 = 0;

    f32x4 acc[4][2];
    #pragma unroll
    for (int i = 0; i < 4; ++i)
        #pragma unroll
        for (int jn = 0; jn < 2; ++jn)
            #pragma unroll
            for (int r = 0; r < 4; ++r) acc[i][jn][r] = 0.f;

    uint4 pa[4], pb[2];
    #pragma unroll
    for (int i = 0; i < 4; ++i) {
        int gg = t + i*256, r = gg >> 3, c = gg & 7;
        pa[i] = *reinterpret_cast<const uint4*>(A + (size_t)(row0 + r)*KD + c*8);
    }
    #pragma unroll
    for (int i = 0; i < 2; ++i) {
        int gg = t + i*256, r = gg >> 3, c = gg & 7;
        pb[i] = *reinterpret_cast<const uint4*>(Wt + (size_t)(n0 + r)*KD + c*8);
    }

    #pragma unroll
    for (int kt = 0; kt < KD; kt += 64) {
        __syncthreads();
        #pragma unroll
        for (int i = 0; i < 4; ++i) {
            int gg = t + i*256, r = gg >> 3, c = gg & 7;
            AsU[r*8 + (c ^ (r & 7))] = pa[i];
        }
        #pragma unroll
        for (int i = 0; i < 2; ++i) {
            int gg = t + i*256, r = gg >> 3, c = gg & 7;
            BsU[r*8 + (c ^ (r & 7))] = pb[i];
        }
        __syncthreads();
        if (kt + 64 < KD) {
            #pragma unroll
            for (int i = 0; i < 4; ++i) {
                int gg = t + i*256, r = gg >> 3, c = gg & 7;
                pa[i] = *reinterpret_cast<const uint4*>(A + (size_t)(row0 + r)*KD + (kt + 64) + c*8);
            }
            #pragma unroll
            for (int i = 0; i < 2; ++i) {
                int gg = t + i*256, r = gg >> 3, c = gg & 7;
                pb[i] = *reinterpret_cast<const uint4*>(Wt + (size_t)(n0 + r)*KD + (kt + 64) + c*8);
            }
        }
        #pragma unroll
        for (int ks = 0; ks < 2; ++ks) {
            int cg = ks*4 + (lane >> 4);
            bf16x8 af[4], bfr[2];
            #pragma unroll
            for (int m = 0; m < 4; ++m) {
                int ar = wm*64 + m*16 + (lane & 15);
                af[m] = Asv[ar*8 + (cg ^ (ar & 7))];
            }
            #pragma unroll
            for (int nn = 0; nn < 2; ++nn) {
                int br = wn*32 + nn*16 + (lane & 15);
                bfr[nn] = Bsv[br*8 + (cg ^ (br & 7))];
            }
            #pragma unroll
            for (int m = 0; m < 4; ++m)
                #pragma unroll
                for (int nn = 0; nn < 2; ++nn)
                    acc[m][nn] = __builtin_amdgcn_mfma_f32_16x16x32_bf16(af[m], bfr[nn], acc[m][nn], 0, 0, 0);
        }
    }

    __syncthreads();
    float* ctile = (float*)smem;
    #pragma unroll
    for (int m = 0; m < 4; ++m) {
        #pragma unroll
        for (int nn = 0; nn < 2; ++nn) {
            int cc = wn*32 + nn*16 + (lane & 15);
            float bcol = bias[n0 + cc];
            #pragma unroll
            for (int r = 0; r < 4; ++r) {
                int rr = wm*64 + m*16 + (lane >> 4)*4 + r;
                ctile[rr*68 + cc] = acc[m][nn][r] + bcol;
            }
        }
    }
    __syncthreads();
    int c4 = (t & 15) * 4;
    #pragma unroll
    for (int rr = t >> 4; rr < 128; rr += 16) {
        float4 v = *reinterpret_cast<const float4*>(ctile + rr*68 + c4);
        *reinterpret_cast<float4*>(Op + (size_t)(row0 + rr)*Nc + n0 + c4) = v;
    }
}

// ---------------- final decoder projection: wave-parallel, transposed f32 Wp ----------------
__global__ __launch_bounds__(512) void final_kernel(
    const bf16* __restrict__ Xh, const float* __restrict__ WpT,
    const float* __restrict__ bp, float* __restrict__ out)
{
    __shared__ float rows[1024];
    int b = blockIdx.x, t = threadIdx.x;
    int lane = t & 63, w = t >> 6;
    const unsigned short* Xu = (const unsigned short*)Xh;
    for (int u = t; u < 1024; u += 512) {
        int g = u >> 8;
        int id = (g == 0) ? 511 : (g == 1) ? 639 : (g == 2) ? 671 : 679;
        rows[u] = bfu2f(Xu[((size_t)(b*NTOK + id))*DM + (u & 255)]);
    }
    __syncthreads();
    #pragma unroll
    for (int oi = 0; oi < 12; ++oi) {
        int o = w*12 + oi;
        float acc = 0.f;
        #pragma unroll
        for (int i = 0; i < 16; ++i) {
            int k = i*64 + lane;
            acc = fmaf(rows[k], WpT[(size_t)o*1024 + k], acc);
        }
        #pragma unroll
        for (int off = 32; off; off >>= 1) acc += __shfl_xor(acc, off);
        if (lane == 0) out[b*96 + o] = acc + bp[o];
    }
}

// ---------------- host launch ----------------
extern "C" void kernel_launch(void* const* d_in, const int* in_sizes, int n_in,
                              void* d_out, int out_size, void* d_ws, size_t ws_size,
                              hipStream_t stream)
{
    const float* x_enc  = (const float*)d_in[0];
    const float* x_mark = (const float*)d_in[1];
    const float* W_val  = (const float*)d_in[2];
    const float* W_time = (const float*)d_in[3];
    const float* b_time = (const float*)d_in[4];
    const float* W_down = (const float*)d_in[5];
    const float* b_down = (const float*)d_in[6];
    const float* W_conv = (const float*)d_in[7];
    const float* b_conv = (const float*)d_in[8];
    const float* bn_g   = (const float*)d_in[9];
    const float* bn_b   = (const float*)d_in[10];
    const float* W_up   = (const float*)d_in[11];
    const float* b_up   = (const float*)d_in[12];
    const float* ln_c_g = (const float*)d_in[13];
    const float* ln_c_b = (const float*)d_in[14];
    const float* Wq     = (const float*)d_in[15];
    const float* bq     = (const float*)d_in[16];
    const float* Wk     = (const float*)d_in[17];
    const float* bk     = (const float*)d_in[18];
    const float* Wv     = (const float*)d_in[19];
    const float* bv     = (const float*)d_in[20];
    const float* Wo     = (const float*)d_in[21];
    const float* bo     = (const float*)d_in[22];
    const float* ln1_g  = (const float*)d_in[23];
    const float* ln1_b  = (const float*)d_in[24];
    const float* W1f    = (const float*)d_in[25];
    const float* b1f    = (const float*)d_in[26];
    const float* W2f    = (const float*)d_in[27];
    const float* b2f    = (const float*)d_in[28];
    const float* ln2_g  = (const float*)d_in[29];
    const float* ln2_b  = (const float*)d_in[30];
    const float* Wp     = (const float*)d_in[31];
    const float* bp     = (const float*)d_in[32];

    const size_t RB = (size_t)NROWS * DM;
    float* ws = (float*)d_ws;
    float* X    = ws;                          // fp32 (prologue only)
    float* Td   = X + RB;
    float* Pool = Td + (size_t)B*SEQ*64;
    float* WpT  = Pool + (size_t)B*168*64;     // [96][1024] f32
    bf16* bws   = (bf16*)(WpT + 96*1024);
    bf16* Xh   = bws;                          // bf16 residual stream
    bf16* Qh   = Xh  + RB;
    bf16* Kh   = Qh  + RB;
    bf16* Vh   = Kh  + RB;
    bf16* Xe   = Vh  + RB;                     // contiguous emb bf16
    bf16* WqT  = Xe  + (size_t)B*SEQ*DM;
    bf16* WkT  = WqT + 2*65536;
    bf16* WvT  = WkT + 2*65536;
    bf16* WoT  = WvT + 2*65536;
    bf16* W1T  = WoT + 2*65536;
    bf16* W2T  = W1T + 2*131072;
    bf16* WdT  = W2T + 2*131072;               // [64][256]
    int*  nbr  = (int*)(WdT + 64*256);
    int*  ncnt = nbr + NTOK*16;

    WTable tbl;
    for (int l = 0; l < 2; ++l) {
        tbl.d[l*6+0] = { Wq  + (size_t)l*65536,  WqT + (size_t)l*65536,  256, 256 };
        tbl.d[l*6+1] = { Wk  + (size_t)l*65536,  WkT + (size_t)l*65536,  256, 256 };
        tbl.d[l*6+2] = { Wv  + (size_t)l*65536,  WvT + (size_t)l*65536,  256, 256 };
        tbl.d[l*6+3] = { Wo  + (size_t)l*65536,  WoT + (size_t)l*65536,  256, 256 };
        tbl.d[l*6+4] = { W1f + (size_t)l*131072, W1T + (size_t)l*131072, 256, 512 };
        tbl.d[l*6+5] = { W2f + (size_t)l*131072, W2T + (size_t)l*131072, 512, 256 };
    }
    tbl.d[12] = { W_down, WdT, 256, 64 };
    wconv_kernel<<<dim3(128, 13), 256, 0, stream>>>(tbl);
    wpt_kernel<<<384, 256, 0, stream>>>(Wp, WpT);

    emb_kernel<<<B*SEQ, 256, 0, stream>>>(x_enc, x_mark, W_val, W_time, b_time, X, Xe);
    mfma_gemm_dn<<<128, 256, 0, stream>>>(Xe, WdT, b_down, Td);
    conv_kernel<<<B*128, 64, 0, stream>>>(Td, 512, 0,   Pool, 0,   128, W_conv, b_conv, bn_g, bn_b, 0);
    conv_kernel<<<B*32,  64, 0, stream>>>(Pool, 168, 0,  Pool, 128, 32,  W_conv, b_conv, bn_g, bn_b, 1);
    conv_kernel<<<B*8,   64, 0, stream>>>(Pool, 168, 128,Pool, 160, 8,   W_conv, b_conv, bn_g, bn_b, 2);
    up_kernel<<<B*168, 256, 0, stream>>>(Pool, W_up, b_up, X);
    ln_kernel<<<NROWS/4, 256, 0, stream>>>(X, Xh, ln_c_g, ln_c_b);
    nbr_kernel<<<11, 64, 0, stream>>>(nbr, ncnt);

    for (int l = 0; l < 2; ++l) {
        const bf16* wqt = WqT + (size_t)l*65536;
        const bf16* wkt = WkT + (size_t)l*65536;
        const bf16* wvt = WvT + (size_t)l*65536;
        const bf16* wot = WoT + (size_t)l*65536;
        const bf16* w1t = W1T + (size_t)l*131072;
        const bf16* w2t = W2T + (size_t)l*131072;
        const float* bq_ = bq + l*DM; const float* bk_ = bk + l*DM;
        const float* bv_ = bv + l*DM; const float* bo_ = bo + l*DM;
        const float* b1_ = b1f + l*FF; const float* b2_ = b2f + l*DM;

        qkv_kernel<<<680, 512, 0, stream>>>(Xh, wqt, wkt, wvt, bq_, bk_, bv_, Qh, Kh, Vh);
        layerfull_kernel<<<680, 512, 0, stream>>>(Qh, Kh, Vh, Xh, wot, bo_,
            ln1_g + l*DM, ln1_b + l*DM, w1t, b1_, w2t, b2_, ln2_g + l*DM, ln2_b + l*DM,
            nbr, ncnt);
    }

    final_kernel<<<B, 512, 0, stream>>>(Xh, WpT, bp, (float*)d_out);
}

// Round 23
// 388.819 us; speedup vs baseline: 1.3734x; 1.3734x over previous
//
#include <hip/hip_runtime.h>
#include <hip/hip_bf16.h>
#include <math.h>

// ---------------- constants ----------------
#define B 32
#define SEQ 512
#define NTOK 680           // 512+128+32+8
#define DM 256
#define FF 512
#define NROWS (B*NTOK)     // 21760

using bf16x8 = __attribute__((ext_vector_type(8))) short;
using f32x4  = __attribute__((ext_vector_type(4))) float;
using u32x4  = __attribute__((ext_vector_type(4))) unsigned int;
typedef __hip_bfloat16 bf16;

__device__ __forceinline__ unsigned short f2bf(float f) {
    union { float f; unsigned u; } x; x.f = f;
    unsigned r = (x.u + 0x7fffu + ((x.u >> 16) & 1u)) >> 16;
    return (unsigned short)r;
}
__device__ __forceinline__ float bfu2f(unsigned short u) {
    union { unsigned u; float f; } x; x.u = ((unsigned)u) << 16;
    return x.f;
}
__device__ __forceinline__ void dotu(unsigned a, unsigned b, float& s) {
    union { unsigned u; float f; } al, ah, bl, bh;
    al.u = a << 16; ah.u = a & 0xffff0000u;
    bl.u = b << 16; bh.u = b & 0xffff0000u;
    s = fmaf(al.f, bl.f, s);
    s = fmaf(ah.f, bh.f, s);
}

// ---------------- embedding (writes fp32 X rows + contiguous bf16 Xe) ----------------
__global__ __launch_bounds__(256) void emb_kernel(
    const float* __restrict__ x_enc, const float* __restrict__ x_mark,
    const float* __restrict__ W_val, const float* __restrict__ W_time,
    const float* __restrict__ b_time, float* __restrict__ X, bf16* __restrict__ Xe)
{
    int bs = blockIdx.x;
    int b = bs >> 9, s = bs & 511;
    int d = threadIdx.x;
    int sm1 = (s + 511) & 511, sp1 = (s + 1) & 511;
    float x0 = x_enc[b*512 + sm1];
    float x1 = x_enc[b*512 + s];
    float x2 = x_enc[b*512 + sp1];
    float val = x0 * W_val[d*3+0] + x1 * W_val[d*3+1] + x2 * W_val[d*3+2];
    const float* mk = &x_mark[(size_t)bs*4];
    float tm = mk[0]*W_time[d] + mk[1]*W_time[256+d] + mk[2]*W_time[512+d] + mk[3]*W_time[768+d];
    int i2 = d & ~1;
    float div = expf((float)i2 * (-9.210340371976184f / 256.0f));
    float ang = (float)s * div;
    float pe = (d & 1) ? cosf(ang) : sinf(ang);
    float out = val + tm + b_time[d] + pe;
    X[((size_t)(b*NTOK + s))*DM + d] = out;
    ((unsigned short*)Xe)[(size_t)bs*DM + d] = f2bf(out);
}

// ---------------- CSCM strided conv + BN affine + ELU ----------------
__global__ __launch_bounds__(64) void conv_kernel(
    const float* __restrict__ in, int inRPB, int inOff,
    float* __restrict__ Pool, int outOff, int Lout,
    const float* __restrict__ W_conv, const float* __restrict__ b_conv,
    const float* __restrict__ bn_g, const float* __restrict__ bn_b, int sc)
{
    __shared__ float lds[256];
    int blk = blockIdx.x;
    int b = blk / Lout, p = blk % Lout;
    int t = threadIdx.x;
    for (int u = t; u < 256; u += 64)
        lds[u] = in[((size_t)(b*inRPB + inOff + p*4 + (u >> 6)))*64 + (u & 63)];
    __syncthreads();
    float acc = b_conv[sc*64 + t];
    const float* w = &W_conv[(size_t)(sc*64 + t)*256];
    #pragma unroll 4
    for (int ci = 0; ci < 64; ++ci) {
        #pragma unroll
        for (int tap = 0; tap < 4; ++tap)
            acc = fmaf(lds[tap*64 + ci], w[ci*4 + tap], acc);
    }
    float v = acc * bn_g[sc*64 + t] + bn_b[sc*64 + t];
    v = v > 0.f ? v : expm1f(v);
    Pool[((size_t)(b*168 + outOff + p))*64 + t] = v;
}

// ---------------- CSCM up-projection ----------------
__global__ __launch_bounds__(256) void up_kernel(
    const float* __restrict__ Pool, const float* __restrict__ W_up,
    const float* __restrict__ b_up, float* __restrict__ X)
{
    __shared__ float row[64];
    int blk = blockIdx.x;
    int b = blk / 168, p = blk % 168;
    int d = threadIdx.x;
    if (d < 64) row[d] = Pool[(size_t)blk*64 + d];
    __syncthreads();
    float acc = b_up[d];
    #pragma unroll 8
    for (int k = 0; k < 64; ++k) acc = fmaf(row[k], W_up[k*256 + d], acc);
    X[((size_t)(b*NTOK + 512 + p))*DM + d] = acc;
}

// ---------------- LayerNorm (prologue): fp32 in, bf16 out ----------------
__global__ __launch_bounds__(256) void ln_kernel(
    const float* __restrict__ Xf, bf16* __restrict__ Xio,
    const float* __restrict__ g, const float* __restrict__ bta)
{
    int r = blockIdx.x*4 + (threadIdx.x >> 6);
    int lane = threadIdx.x & 63;
    float4 v = ((const float4*)(Xf + (size_t)r*DM))[lane];
    float s = v.x + v.y + v.z + v.w;
    #pragma unroll
    for (int o = 32; o; o >>= 1) s += __shfl_xor(s, o);
    float mean = s * (1.0f/256.0f);
    float dx = v.x-mean, dy = v.y-mean, dz = v.z-mean, dw = v.w-mean;
    float q = dx*dx + dy*dy + dz*dz + dw*dw;
    #pragma unroll
    for (int o = 32; o; o >>= 1) q += __shfl_xor(q, o);
    float inv = rsqrtf(q*(1.0f/256.0f) + 1e-5f);
    float4 gg = ((const float4*)g)[lane];
    float4 bb = ((const float4*)bta)[lane];
    float ox = dx*inv*gg.x + bb.x;
    float oy = dy*inv*gg.y + bb.y;
    float oz = dz*inv*gg.z + bb.z;
    float ow = dw*inv*gg.w + bb.w;
    unsigned u0 = (unsigned)f2bf(ox) | ((unsigned)f2bf(oy) << 16);
    unsigned u1 = (unsigned)f2bf(oz) | ((unsigned)f2bf(ow) << 16);
    ((uint2*)(Xio + (size_t)r*DM))[lane] = make_uint2(u0, u1);
}

// ---------------- neighbor lists: closed form ----------------
__global__ void nbr_kernel(int* __restrict__ nbr, int* __restrict__ ncnt)
{
    int i = blockIdx.x * 64 + threadIdx.x;
    if (i >= NTOK) return;
    const int starts[5] = {0, 512, 640, 672, 680};
    int si = (i < 512) ? 0 : (i < 640) ? 1 : (i < 672) ? 2 : 3;
    int st = starts[si], en = starts[si+1];
    int idx = i - st;
    int cnt = 0;
    if (si >= 1) {
        int cs = starts[si-1] + idx*4;
        #pragma unroll
        for (int c = 0; c < 4; ++c) nbr[i*16 + cnt++] = cs + c;
    }
    int lo = (i-2 > st) ? i-2 : st;
    int hi = (i+2 < en-1) ? i+2 : en-1;
    for (int j = lo; j <= hi; ++j) nbr[i*16 + cnt++] = j;
    if (si <= 2) nbr[i*16 + cnt++] = starts[si+1] + (idx >> 2);
    ncnt[i] = cnt;
}

// ---------------- sparse masked attention, wave-parallel ----------------
__global__ __launch_bounds__(256) void attn_kernel(
    const bf16* __restrict__ Q, const bf16* __restrict__ K,
    const bf16* __restrict__ V, bf16* __restrict__ O,
    const int* __restrict__ nbr, const int* __restrict__ ncnt)
{
    __shared__ float wsm[4][16];
    __shared__ int   jsm[4][16];
    int flat = blockIdx.x;
    int row = (flat & 7) * (NROWS/8) + (flat >> 3);   // XCD-contiguous rows
    int n = row % NTOK, b = row / NTOK;
    int h = threadIdx.x >> 6;
    int lane = threadIdx.x & 63;
    int j = lane >> 2, g = lane & 3;
    int cnt = ncnt[n];
    int nj = (j < cnt) ? nbr[n*16 + j] : n;
    int jr = b*NTOK + nj;

    const uint4* qp = (const uint4*)(Q + (size_t)row*DM + h*64 + g*16);
    const uint4* kp = (const uint4*)(K + (size_t)jr*DM + h*64 + g*16);
    uint4 qa = qp[0], qb = qp[1];
    uint4 ka = kp[0], kb = kp[1];
    float s = 0.f;
    dotu(qa.x, ka.x, s); dotu(qa.y, ka.y, s); dotu(qa.z, ka.z, s); dotu(qa.w, ka.w, s);
    dotu(qb.x, kb.x, s); dotu(qb.y, kb.y, s); dotu(qb.z, kb.z, s); dotu(qb.w, kb.w, s);
    s += __shfl_xor(s, 1);
    s += __shfl_xor(s, 2);
    s *= 0.125f;
    if (j >= cnt) s = -1e30f;
    float m = s;
    #pragma unroll
    for (int o = 4; o < 64; o <<= 1) m = fmaxf(m, __shfl_xor(m, o));
    float w = (j < cnt) ? expf(s - m) : 0.f;
    float den = w;
    #pragma unroll
    for (int o = 4; o < 64; o <<= 1) den += __shfl_xor(den, o);
    if (g == 0) { wsm[h][j] = w / den; jsm[h][j] = jr; }
    __syncthreads();

    float acc = 0.f;
    const unsigned short* Vu = (const unsigned short*)V;
    for (int jj = 0; jj < cnt; ++jj) {
        float wv = wsm[h][jj];
        int rr = jsm[h][jj];
        acc = fmaf(wv, bfu2f(Vu[(size_t)rr*DM + h*64 + lane]), acc);
    }
    ((unsigned short*)O)[(size_t)row*DM + h*64 + lane] = f2bf(acc);
}

// ---------------- weight transpose + bf16 convert: 32x32 LDS tiles ----------------
struct WDesc { const float* src; bf16* dst; int K; int N; };
struct WTable { WDesc d[13]; };
__global__ __launch_bounds__(256) void wconv_kernel(WTable tbl)
{
    __shared__ float lds[32][33];
    WDesc ds = tbl.d[blockIdx.y];
    int ntn = ds.N >> 5;
    int ntiles = (ds.K >> 5) * ntn;
    int tile = blockIdx.x;
    if (tile >= ntiles) return;
    int k0 = (tile / ntn) * 32, n0 = (tile % ntn) * 32;
    int t = threadIdx.x;
    int r = t >> 3, c4 = (t & 7) * 4;
    float4 v = *(const float4*)(ds.src + (size_t)(k0 + r)*ds.N + n0 + c4);
    lds[r][c4+0] = v.x; lds[r][c4+1] = v.y; lds[r][c4+2] = v.z; lds[r][c4+3] = v.w;
    __syncthreads();
    unsigned u0 = (unsigned)f2bf(lds[c4+0][r]) | ((unsigned)f2bf(lds[c4+1][r]) << 16);
    unsigned u1 = (unsigned)f2bf(lds[c4+2][r]) | ((unsigned)f2bf(lds[c4+3][r]) << 16);
    *(uint2*)((unsigned short*)ds.dst + (size_t)(n0 + r)*ds.K + k0 + c4) = make_uint2(u0, u1);
}

// ---------------- Wp transpose (f32): WpT[o][k] = Wp[k][o] ----------------
__global__ __launch_bounds__(256) void wpt_kernel(
    const float* __restrict__ Wp, float* __restrict__ WpT)
{
    int e = blockIdx.x*256 + threadIdx.x;
    int o = e % 96, k = e / 96;
    WpT[(size_t)o*1024 + k] = Wp[(size_t)k*96 + o];
}

// ---------------- FUSED QKV projection (32 rows, 8 waves, weight prefetch) ----------------
__global__ __launch_bounds__(512, 2) void qkv_kernel(
    const bf16* __restrict__ Xh,
    const bf16* __restrict__ WqT, const bf16* __restrict__ WkT, const bf16* __restrict__ WvT,
    const float* __restrict__ bq, const float* __restrict__ bk, const float* __restrict__ bv,
    bf16* __restrict__ Qh, bf16* __restrict__ Kh, bf16* __restrict__ Vh)
{
    __shared__ __align__(16) char smem[16384 + 16896];   // A 16KB | ctb [32][264] bf16
    uint4* AsU = (uint4*)smem;
    const bf16x8* Asv = (const bf16x8*)smem;
    unsigned short* ctb = (unsigned short*)(smem + 16384);

    int t = threadIdx.x;
    int lane = t & 63, w = t >> 6;
    int nwg = gridDim.x;                                 // 680, %8==0
    int wg = (blockIdx.x & 7) * (nwg >> 3) + (blockIdx.x >> 3);
    int row0 = wg * 32;
    const unsigned short* Xu = (const unsigned short*)Xh;

    #pragma unroll
    for (int i = 0; i < 2; ++i) {
        int gg = t + i*512, r = gg >> 5, c = gg & 31;
        AsU[r*32 + (c ^ (r & 7))] = *(const uint4*)(Xu + (size_t)(row0 + r)*DM + c*8);
    }
    __syncthreads();

    #pragma unroll
    for (int z = 0; z < 3; ++z) {
        const unsigned short* Wu = (const unsigned short*)((z == 0) ? WqT : (z == 1) ? WkT : WvT);
        const float* bias = (z == 0) ? bq : (z == 1) ? bk : bv;
        bf16* Op = (z == 0) ? Qh : (z == 1) ? Kh : Vh;

        f32x4 acc[2][2];
        #pragma unroll
        for (int m = 0; m < 2; ++m)
            #pragma unroll
            for (int nn = 0; nn < 2; ++nn)
                #pragma unroll
                for (int q = 0; q < 4; ++q) acc[m][nn][q] = 0.f;
        float bv_[2];
        #pragma unroll
        for (int nn = 0; nn < 2; ++nn) bv_[nn] = bias[w*32 + nn*16 + (lane & 15)];

        #pragma unroll
        for (int kh = 0; kh < 2; ++kh) {
            bf16x8 pw[8];
            #pragma unroll
            for (int i = 0; i < 8; ++i) {
                int kt = kh*128 + (i >> 1)*32, nn = i & 1;
                int nrow = w*32 + nn*16 + (lane & 15);
                pw[i] = *(const bf16x8*)(Wu + (size_t)nrow*256 + kt + (lane >> 4)*8);
            }
            #pragma unroll
            for (int ki = 0; ki < 4; ++ki) {
                int kt = kh*128 + ki*32;
                int cg = (kt >> 3) + (lane >> 4);
                bf16x8 af[2];
                #pragma unroll
                for (int m = 0; m < 2; ++m) {
                    int ar = m*16 + (lane & 15);
                    af[m] = Asv[ar*32 + (cg ^ (ar & 7))];
                }
                #pragma unroll
                for (int nn = 0; nn < 2; ++nn)
                    #pragma unroll
                    for (int m = 0; m < 2; ++m)
                        acc[m][nn] = __builtin_amdgcn_mfma_f32_16x16x32_bf16(af[m], pw[ki*2+nn], acc[m][nn], 0, 0, 0);
            }
        }

        __syncthreads();
        #pragma unroll
        for (int m = 0; m < 2; ++m)
            #pragma unroll
            for (int nn = 0; nn < 2; ++nn) {
                int col = w*32 + nn*16 + (lane & 15);
                #pragma unroll
                for (int q = 0; q < 4; ++q) {
                    int row = m*16 + (lane >> 4)*4 + q;
                    ctb[row*264 + col] = f2bf(acc[m][nn][q] + bv_[nn]);
                }
            }
        __syncthreads();
        #pragma unroll
        for (int i = 0; i < 2; ++i) {
            int idx = t + i*512;
            int row = idx >> 5, c16 = idx & 31;
            u32x4 uv = *(const u32x4*)(ctb + row*264 + c16*8);
            *(u32x4*)((unsigned short*)Op + (size_t)(row0 + row)*DM + c16*8) = uv;
        }
    }
}

// ---------------- FUSED Wo+LN1+FFN+LN2 (32 rows, 8 waves, merged FF1 halves) ----------------
#define CSTR 260
#define HSTR2 520
__global__ __launch_bounds__(512, 2) void layer2_kernel(
    const bf16* __restrict__ Ob, bf16* __restrict__ Xh,
    const bf16* __restrict__ WoT, const float* __restrict__ bo,
    const float* __restrict__ g1, const float* __restrict__ b1n,
    const bf16* __restrict__ W1t, const float* __restrict__ b1,
    const bf16* __restrict__ W2t, const float* __restrict__ b2,
    const float* __restrict__ g2, const float* __restrict__ b2n)
{
    __shared__ __align__(16) char smem[16384 + 33280];   // A 16KB | union(ctile f32 [32][260], hT bf16 [32][520])
    uint4* AsU = (uint4*)smem;
    const bf16x8* Asv = (const bf16x8*)smem;
    unsigned short* Asu16 = (unsigned short*)smem;
    float* ctile = (float*)(smem + 16384);
    unsigned short* hT = (unsigned short*)(smem + 16384);

    int t = threadIdx.x;
    int lane = t & 63, w = t >> 6;
    int nwg = gridDim.x;                                 // 680
    int wg = (blockIdx.x & 7) * (nwg >> 3) + (blockIdx.x >> 3);
    int row0 = wg * 32;
    const unsigned short* Obu = (const unsigned short*)Ob;
    const unsigned short* Xu  = (const unsigned short*)Xh;
    const unsigned short* WoU = (const unsigned short*)WoT;
    const unsigned short* W1u = (const unsigned short*)W1t;
    const unsigned short* W2u = (const unsigned short*)W2t;

    // ---- stage Ob tile
    #pragma unroll
    for (int i = 0; i < 2; ++i) {
        int gg = t + i*512, r = gg >> 5, c = gg & 31;
        AsU[r*32 + (c ^ (r & 7))] = *(const uint4*)(Obu + (size_t)(row0 + r)*DM + c*8);
    }
    __syncthreads();                                     // (1)

    // ---- Wo projection -> ctile
    {
        f32x4 acc[2][2];
        #pragma unroll
        for (int m = 0; m < 2; ++m)
            #pragma unroll
            for (int nn = 0; nn < 2; ++nn)
                #pragma unroll
                for (int q = 0; q < 4; ++q) acc[m][nn][q] = 0.f;
        float bvv[2];
        #pragma unroll
        for (int nn = 0; nn < 2; ++nn) bvv[nn] = bo[w*32 + nn*16 + (lane & 15)];

        #pragma unroll
        for (int kh = 0; kh < 2; ++kh) {
            bf16x8 pw[8];
            #pragma unroll
            for (int i = 0; i < 8; ++i) {
                int kt = kh*128 + (i >> 1)*32, nn = i & 1;
                int nrow = w*32 + nn*16 + (lane & 15);
                pw[i] = *(const bf16x8*)(WoU + (size_t)nrow*256 + kt + (lane >> 4)*8);
            }
            #pragma unroll
            for (int ki = 0; ki < 4; ++ki) {
                int kt = kh*128 + ki*32;
                int cg = (kt >> 3) + (lane >> 4);
                bf16x8 af[2];
                #pragma unroll
                for (int m = 0; m < 2; ++m) {
                    int ar = m*16 + (lane & 15);
                    af[m] = Asv[ar*32 + (cg ^ (ar & 7))];
                }
                #pragma unroll
                for (int nn = 0; nn < 2; ++nn)
                    #pragma unroll
                    for (int m = 0; m < 2; ++m)
                        acc[m][nn] = __builtin_amdgcn_mfma_f32_16x16x32_bf16(af[m], pw[ki*2+nn], acc[m][nn], 0, 0, 0);
            }
        }

        #pragma unroll
        for (int m = 0; m < 2; ++m)
            #pragma unroll
            for (int nn = 0; nn < 2; ++nn) {
                int col = w*32 + nn*16 + (lane & 15);
                #pragma unroll
                for (int q = 0; q < 4; ++q) {
                    int row = m*16 + (lane >> 4)*4 + q;
                    ctile[row*CSTR + col] = acc[m][nn][q] + bvv[nn];
                }
            }
    }
    __syncthreads();                                     // (2)

    // ---- LN1: xmid = LN(ctile + Xh); write xmid bf16 into AsU (swizzled)
    #pragma unroll
    for (int rr = 0; rr < 4; ++rr) {
        int row = w*4 + rr;
        float4 v = *(const float4*)(ctile + row*CSTR + lane*4);
        uint2 xu = *(const uint2*)(Xu + (size_t)(row0 + row)*DM + lane*4);
        v.x += bfu2f((unsigned short)(xu.x & 0xffffu));
        v.y += bfu2f((unsigned short)(xu.x >> 16));
        v.z += bfu2f((unsigned short)(xu.y & 0xffffu));
        v.w += bfu2f((unsigned short)(xu.y >> 16));
        float s = v.x + v.y + v.z + v.w;
        #pragma unroll
        for (int o = 32; o; o >>= 1) s += __shfl_xor(s, o);
        float mean = s * (1.0f/256.0f);
        float dx = v.x-mean, dy = v.y-mean, dz = v.z-mean, dw = v.w-mean;
        float q2 = dx*dx + dy*dy + dz*dz + dw*dw;
        #pragma unroll
        for (int o = 32; o; o >>= 1) q2 += __shfl_xor(q2, o);
        float inv = rsqrtf(q2*(1.0f/256.0f) + 1e-5f);
        float4 gg = ((const float4*)g1)[lane];
        float4 bb = ((const float4*)b1n)[lane];
        float ox = dx*inv*gg.x + bb.x;
        float oy = dy*inv*gg.y + bb.y;
        float oz = dz*inv*gg.z + bb.z;
        float ow = dw*inv*gg.w + bb.w;
        unsigned u0 = (unsigned)f2bf(ox) | ((unsigned)f2bf(oy) << 16);
        unsigned u1 = (unsigned)f2bf(oz) | ((unsigned)f2bf(ow) << 16);
        *(uint2*)(Asu16 + row*256 + (((lane>>1) ^ (row & 7))*8) + (lane & 1)*4) = make_uint2(u0, u1);
    }
    __syncthreads();                                     // (3)

    // ---- FF1: both halves in registers (64 hidden cols per wave)
    f32x4 acc1[2][2][2];   // [half][m][nn]
    #pragma unroll
    for (int hf = 0; hf < 2; ++hf)
        #pragma unroll
        for (int m = 0; m < 2; ++m)
            #pragma unroll
            for (int nn = 0; nn < 2; ++nn)
                #pragma unroll
                for (int q = 0; q < 4; ++q) acc1[hf][m][nn][q] = 0.f;

    #pragma unroll
    for (int hf = 0; hf < 2; ++hf) {
        #pragma unroll
        for (int kh = 0; kh < 2; ++kh) {
            bf16x8 pw[8];
            #pragma unroll
            for (int i = 0; i < 8; ++i) {
                int kt = kh*128 + (i >> 1)*32, nn = i & 1;
                int nrow = hf*256 + w*32 + nn*16 + (lane & 15);
                pw[i] = *(const bf16x8*)(W1u + (size_t)nrow*256 + kt + (lane >> 4)*8);
            }
            #pragma unroll
            for (int ki = 0; ki < 4; ++ki) {
                int kt = kh*128 + ki*32;
                int cg = (kt >> 3) + (lane >> 4);
                bf16x8 af[2];
                #pragma unroll
                for (int m = 0; m < 2; ++m) {
                    int ar = m*16 + (lane & 15);
                    af[m] = Asv[ar*32 + (cg ^ (ar & 7))];
                }
                #pragma unroll
                for (int nn = 0; nn < 2; ++nn)
                    #pragma unroll
                    for (int m = 0; m < 2; ++m)
                        acc1[hf][m][nn] = __builtin_amdgcn_mfma_f32_16x16x32_bf16(af[m], pw[ki*2+nn], acc1[hf][m][nn], 0, 0, 0);
            }
        }
    }
    #pragma unroll
    for (int hf = 0; hf < 2; ++hf) {
        float b1v[2];
        #pragma unroll
        for (int nn = 0; nn < 2; ++nn) b1v[nn] = b1[hf*256 + w*32 + nn*16 + (lane & 15)];
        #pragma unroll
        for (int m = 0; m < 2; ++m)
            #pragma unroll
            for (int nn = 0; nn < 2; ++nn) {
                int col = hf*256 + w*32 + nn*16 + (lane & 15);
                #pragma unroll
                for (int q = 0; q < 4; ++q) {
                    int row = m*16 + (lane >> 4)*4 + q;
                    hT[row*HSTR2 + col] = f2bf(fmaxf(acc1[hf][m][nn][q] + b1v[nn], 0.f));
                }
            }
    }
    __syncthreads();                                     // (4)

    // ---- FF2: single K=512 sweep
    f32x4 acc2[2][2];
    #pragma unroll
    for (int m = 0; m < 2; ++m)
        #pragma unroll
        for (int nn = 0; nn < 2; ++nn)
            #pragma unroll
            for (int q = 0; q < 4; ++q) acc2[m][nn][q] = 0.f;
    float b2v[2];
    #pragma unroll
    for (int nn = 0; nn < 2; ++nn) b2v[nn] = b2[w*32 + nn*16 + (lane & 15)];

    #pragma unroll
    for (int kh = 0; kh < 4; ++kh) {
        bf16x8 pw[8];
        #pragma unroll
        for (int i = 0; i < 8; ++i) {
            int kt = kh*128 + (i >> 1)*32, nn = i & 1;
            int nrow = w*32 + nn*16 + (lane & 15);
            pw[i] = *(const bf16x8*)(W2u + (size_t)nrow*512 + kt + (lane >> 4)*8);
        }
        #pragma unroll
        for (int ki = 0; ki < 4; ++ki) {
            int kt = kh*128 + ki*32;
            bf16x8 af[2];
            #pragma unroll
            for (int m = 0; m < 2; ++m) {
                int ar = m*16 + (lane & 15);
                af[m] = *(const bf16x8*)(hT + ar*HSTR2 + kt + (lane >> 4)*8);
            }
            #pragma unroll
            for (int nn = 0; nn < 2; ++nn)
                #pragma unroll
                for (int m = 0; m < 2; ++m)
                    acc2[m][nn] = __builtin_amdgcn_mfma_f32_16x16x32_bf16(af[m], pw[ki*2+nn], acc2[m][nn], 0, 0, 0);
        }
    }
    __syncthreads();                                     // (5)

    // ---- epilogue: ctile = acc2 + b2
    #pragma unroll
    for (int m = 0; m < 2; ++m)
        #pragma unroll
        for (int nn = 0; nn < 2; ++nn) {
            int col = w*32 + nn*16 + (lane & 15);
            #pragma unroll
            for (int q = 0; q < 4; ++q) {
                int row = m*16 + (lane >> 4)*4 + q;
                ctile[row*CSTR + col] = acc2[m][nn][q] + b2v[nn];
            }
        }
    __syncthreads();                                     // (6)
    // ---- LN2: Xh = LN(ctile + xmid from AsU)
    #pragma unroll
    for (int rr = 0; rr < 4; ++rr) {
        int row = w*4 + rr;
        float4 v = *(const float4*)(ctile + row*CSTR + lane*4);
        uint2 xu = *(const uint2*)(Asu16 + row*256 + (((lane>>1) ^ (row & 7))*8) + (lane & 1)*4);
        v.x += bfu2f((unsigned short)(xu.x & 0xffffu));
        v.y += bfu2f((unsigned short)(xu.x >> 16));
        v.z += bfu2f((unsigned short)(xu.y & 0xffffu));
        v.w += bfu2f((unsigned short)(xu.y >> 16));
        float s = v.x + v.y + v.z + v.w;
        #pragma unroll
        for (int o = 32; o; o >>= 1) s += __shfl_xor(s, o);
        float mean = s * (1.0f/256.0f);
        float dx = v.x-mean, dy = v.y-mean, dz = v.z-mean, dw = v.w-mean;
        float q2 = dx*dx + dy*dy + dz*dz + dw*dw;
        #pragma unroll
        for (int o = 32; o; o >>= 1) q2 += __shfl_xor(q2, o);
        float inv = rsqrtf(q2*(1.0f/256.0f) + 1e-5f);
        float4 gg = ((const float4*)g2)[lane];
        float4 bb = ((const float4*)b2n)[lane];
        float ox = dx*inv*gg.x + bb.x;
        float oy = dy*inv*gg.y + bb.y;
        float oz = dz*inv*gg.z + bb.z;
        float ow = dw*inv*gg.w + bb.w;
        unsigned u0 = (unsigned)f2bf(ox) | ((unsigned)f2bf(oy) << 16);
        unsigned u1 = (unsigned)f2bf(oz) | ((unsigned)f2bf(ow) << 16);
        *(uint2*)((unsigned short*)Xh + (size_t)(row0 + row)*DM + lane*4) = make_uint2(u0, u1);
    }
}

// ---------------- MFMA bf16 GEMM, 128x64 (down-projection, f32 out) ----------------
__global__ __launch_bounds__(256) void mfma_gemm_dn(
    const bf16* __restrict__ A, const bf16* __restrict__ Wt,
    const float* __restrict__ bias, float* __restrict__ Op)
{
    __shared__ __align__(16) char smem[34816];
    uint4* AsU = (uint4*)smem;
    uint4* BsU = (uint4*)(smem + 16384);
    const bf16x8* Asv = (const bf16x8*)smem;
    const bf16x8* Bsv = (const bf16x8*)(smem + 16384);
    const int KD = 256, Nc = 64;

    int t = threadIdx.x;
    int lane = t & 63, wid = t >> 6;
    int wm = wid >> 1, wn = wid & 1;
    int nwg = gridDim.x;
    int wg = (blockIdx.x & 7) * (nwg >> 3) + (blockIdx.x >> 3);
    int row0 = wg * 128;
    int n0 = 0;

    f32x4 acc[4][2];
    #pragma unroll
    for (int i = 0; i < 4; ++i)
        #pragma unroll
        for (int jn = 0; jn < 2; ++jn)
            #pragma unroll
            for (int r = 0; r < 4; ++r) acc[i][jn][r] = 0.f;

    uint4 pa[4], pb[2];
    #pragma unroll
    for (int i = 0; i < 4; ++i) {
        int gg = t + i*256, r = gg >> 3, c = gg & 7;
        pa[i] = *reinterpret_cast<const uint4*>(A + (size_t)(row0 + r)*KD + c*8);
    }
    #pragma unroll
    for (int i = 0; i < 2; ++i) {
        int gg = t + i*256, r = gg >> 3, c = gg & 7;
        pb[i] = *reinterpret_cast<const uint4*>(Wt + (size_t)(n0 + r)*KD + c*8);
    }

    #pragma unroll
    for (int kt = 0; kt < KD; kt += 64) {
        __syncthreads();
        #pragma unroll
        for (int i = 0; i < 4; ++i) {
            int gg = t + i*256, r = gg >> 3, c = gg & 7;
            AsU[r*8 + (c ^ (r & 7))] = pa[i];
        }
        #pragma unroll
        for (int i = 0; i < 2; ++i) {
            int gg = t + i*256, r = gg >> 3, c = gg & 7;
            BsU[r*8 + (c ^ (r & 7))] = pb[i];
        }
        __syncthreads();
        if (kt + 64 < KD) {
            #pragma unroll
            for (int i = 0; i < 4; ++i) {
                int gg = t + i*256, r = gg >> 3, c = gg & 7;
                pa[i] = *reinterpret_cast<const uint4*>(A + (size_t)(row0 + r)*KD + (kt + 64) + c*8);
            }
            #pragma unroll
            for (int i = 0; i < 2; ++i) {
                int gg = t + i*256, r = gg >> 3, c = gg & 7;
                pb[i] = *reinterpret_cast<const uint4*>(Wt + (size_t)(n0 + r)*KD + (kt + 64) + c*8);
            }
        }
        #pragma unroll
        for (int ks = 0; ks < 2; ++ks) {
            int cg = ks*4 + (lane >> 4);
            bf16x8 af[4], bfr[2];
            #pragma unroll
            for (int m = 0; m < 4; ++m) {
                int ar = wm*64 + m*16 + (lane & 15);
                af[m] = Asv[ar*8 + (cg ^ (ar & 7))];
            }
            #pragma unroll
            for (int nn = 0; nn < 2; ++nn) {
                int br = wn*32 + nn*16 + (lane & 15);
                bfr[nn] = Bsv[br*8 + (cg ^ (br & 7))];
            }
            #pragma unroll
            for (int m = 0; m < 4; ++m)
                #pragma unroll
                for (int nn = 0; nn < 2; ++nn)
                    acc[m][nn] = __builtin_amdgcn_mfma_f32_16x16x32_bf16(af[m], bfr[nn], acc[m][nn], 0, 0, 0);
        }
    }

    __syncthreads();
    float* ctile = (float*)smem;
    #pragma unroll
    for (int m = 0; m < 4; ++m) {
        #pragma unroll
        for (int nn = 0; nn < 2; ++nn) {
            int cc = wn*32 + nn*16 + (lane & 15);
            float bcol = bias[n0 + cc];
            #pragma unroll
            for (int r = 0; r < 4; ++r) {
                int rr = wm*64 + m*16 + (lane >> 4)*4 + r;
                ctile[rr*68 + cc] = acc[m][nn][r] + bcol;
            }
        }
    }
    __syncthreads();
    int c4 = (t & 15) * 4;
    #pragma unroll
    for (int rr = t >> 4; rr < 128; rr += 16) {
        float4 v = *reinterpret_cast<const float4*>(ctile + rr*68 + c4);
        *reinterpret_cast<float4*>(Op + (size_t)(row0 + rr)*Nc + n0 + c4) = v;
    }
}

// ---------------- final decoder projection: wave-parallel, transposed f32 Wp ----------------
__global__ __launch_bounds__(512) void final_kernel(
    const bf16* __restrict__ Xh, const float* __restrict__ WpT,
    const float* __restrict__ bp, float* __restrict__ out)
{
    __shared__ float rows[1024];
    int b = blockIdx.x, t = threadIdx.x;
    int lane = t & 63, w = t >> 6;
    const unsigned short* Xu = (const unsigned short*)Xh;
    for (int u = t; u < 1024; u += 512) {
        int g = u >> 8;
        int id = (g == 0) ? 511 : (g == 1) ? 639 : (g == 2) ? 671 : 679;
        rows[u] = bfu2f(Xu[((size_t)(b*NTOK + id))*DM + (u & 255)]);
    }
    __syncthreads();
    #pragma unroll
    for (int oi = 0; oi < 12; ++oi) {
        int o = w*12 + oi;
        float acc = 0.f;
        #pragma unroll
        for (int i = 0; i < 16; ++i) {
            int k = i*64 + lane;
            acc = fmaf(rows[k], WpT[(size_t)o*1024 + k], acc);
        }
        #pragma unroll
        for (int off = 32; off; off >>= 1) acc += __shfl_xor(acc, off);
        if (lane == 0) out[b*96 + o] = acc + bp[o];
    }
}

// ---------------- host launch ----------------
extern "C" void kernel_launch(void* const* d_in, const int* in_sizes, int n_in,
                              void* d_out, int out_size, void* d_ws, size_t ws_size,
                              hipStream_t stream)
{
    const float* x_enc  = (const float*)d_in[0];
    const float* x_mark = (const float*)d_in[1];
    const float* W_val  = (const float*)d_in[2];
    const float* W_time = (const float*)d_in[3];
    const float* b_time = (const float*)d_in[4];
    const float* W_down = (const float*)d_in[5];
    const float* b_down = (const float*)d_in[6];
    const float* W_conv = (const float*)d_in[7];
    const float* b_conv = (const float*)d_in[8];
    const float* bn_g   = (const float*)d_in[9];
    const float* bn_b   = (const float*)d_in[10];
    const float* W_up   = (const float*)d_in[11];
    const float* b_up   = (const float*)d_in[12];
    const float* ln_c_g = (const float*)d_in[13];
    const float* ln_c_b = (const float*)d_in[14];
    const float* Wq     = (const float*)d_in[15];
    const float* bq     = (const float*)d_in[16];
    const float* Wk     = (const float*)d_in[17];
    const float* bk     = (const float*)d_in[18];
    const float* Wv     = (const float*)d_in[19];
    const float* bv     = (const float*)d_in[20];
    const float* Wo     = (const float*)d_in[21];
    const float* bo     = (const float*)d_in[22];
    const float* ln1_g  = (const float*)d_in[23];
    const float* ln1_b  = (const float*)d_in[24];
    const float* W1f    = (const float*)d_in[25];
    const float* b1f    = (const float*)d_in[26];
    const float* W2f    = (const float*)d_in[27];
    const float* b2f    = (const float*)d_in[28];
    const float* ln2_g  = (const float*)d_in[29];
    const float* ln2_b  = (const float*)d_in[30];
    const float* Wp     = (const float*)d_in[31];
    const float* bp     = (const float*)d_in[32];

    const size_t RB = (size_t)NROWS * DM;
    float* ws = (float*)d_ws;
    float* X    = ws;                          // fp32 (prologue only)
    float* Td   = X + RB;
    float* Pool = Td + (size_t)B*SEQ*64;
    float* WpT  = Pool + (size_t)B*168*64;     // [96][1024] f32
    bf16* bws   = (bf16*)(WpT + 96*1024);
    bf16* Xh   = bws;                          // bf16 residual stream
    bf16* Qh   = Xh  + RB;
    bf16* Kh   = Qh  + RB;
    bf16* Vh   = Kh  + RB;
    bf16* Obh  = Vh  + RB;
    bf16* Xe   = Obh + RB;                     // contiguous emb bf16
    bf16* WqT  = Xe  + (size_t)B*SEQ*DM;
    bf16* WkT  = WqT + 2*65536;
    bf16* WvT  = WkT + 2*65536;
    bf16* WoT  = WvT + 2*65536;
    bf16* W1T  = WoT + 2*65536;
    bf16* W2T  = W1T + 2*131072;
    bf16* WdT  = W2T + 2*131072;               // [64][256]
    int*  nbr  = (int*)(WdT + 64*256);
    int*  ncnt = nbr + NTOK*16;

    WTable tbl;
    for (int l = 0; l < 2; ++l) {
        tbl.d[l*6+0] = { Wq  + (size_t)l*65536,  WqT + (size_t)l*65536,  256, 256 };
        tbl.d[l*6+1] = { Wk  + (size_t)l*65536,  WkT + (size_t)l*65536,  256, 256 };
        tbl.d[l*6+2] = { Wv  + (size_t)l*65536,  WvT + (size_t)l*65536,  256, 256 };
        tbl.d[l*6+3] = { Wo  + (size_t)l*65536,  WoT + (size_t)l*65536,  256, 256 };
        tbl.d[l*6+4] = { W1f + (size_t)l*131072, W1T + (size_t)l*131072, 256, 512 };
        tbl.d[l*6+5] = { W2f + (size_t)l*131072, W2T + (size_t)l*131072, 512, 256 };
    }
    tbl.d[12] = { W_down, WdT, 256, 64 };
    wconv_kernel<<<dim3(128, 13), 256, 0, stream>>>(tbl);
    wpt_kernel<<<384, 256, 0, stream>>>(Wp, WpT);

    emb_kernel<<<B*SEQ, 256, 0, stream>>>(x_enc, x_mark, W_val, W_time, b_time, X, Xe);
    mfma_gemm_dn<<<128, 256, 0, stream>>>(Xe, WdT, b_down, Td);
    conv_kernel<<<B*128, 64, 0, stream>>>(Td, 512, 0,   Pool, 0,   128, W_conv, b_conv, bn_g, bn_b, 0);
    conv_kernel<<<B*32,  64, 0, stream>>>(Pool, 168, 0,  Pool, 128, 32,  W_conv, b_conv, bn_g, bn_b, 1);
    conv_kernel<<<B*8,   64, 0, stream>>>(Pool, 168, 128,Pool, 160, 8,   W_conv, b_conv, bn_g, bn_b, 2);
    up_kernel<<<B*168, 256, 0, stream>>>(Pool, W_up, b_up, X);
    ln_kernel<<<NROWS/4, 256, 0, stream>>>(X, Xh, ln_c_g, ln_c_b);
    nbr_kernel<<<11, 64, 0, stream>>>(nbr, ncnt);

    for (int l = 0; l < 2; ++l) {
        const bf16* wqt = WqT + (size_t)l*65536;
        const bf16* wkt = WkT + (size_t)l*65536;
        const bf16* wvt = WvT + (size_t)l*65536;
        const bf16* wot = WoT + (size_t)l*65536;
        const bf16* w1t = W1T + (size_t)l*131072;
        const bf16* w2t = W2T + (size_t)l*131072;
        const float* bq_ = bq + l*DM; const float* bk_ = bk + l*DM;
        const float* bv_ = bv + l*DM; const float* bo_ = bo + l*DM;
        const float* b1_ = b1f + l*FF; const float* b2_ = b2f + l*DM;

        qkv_kernel<<<680, 512, 0, stream>>>(Xh, wqt, wkt, wvt, bq_, bk_, bv_, Qh, Kh, Vh);
        attn_kernel<<<NROWS, 256, 0, stream>>>(Qh, Kh, Vh, Obh, nbr, ncnt);
        layer2_kernel<<<680, 512, 0, stream>>>(Obh, Xh, wot, bo_,
            ln1_g + l*DM, ln1_b + l*DM, w1t, b1_, w2t, b2_, ln2_g + l*DM, ln2_b + l*DM);
    }

    final_kernel<<<B, 512, 0, stream>>>(Xh, WpT, bp, (float*)d_out);
}